// Round 1
// baseline (1096.769 us; speedup 1.0000x reference)
//
#include <hip/hip_runtime.h>
#include <stdint.h>

#define G3          (256 * 256 * 256)        // 16,777,216 cells per cascade
#define CASCADES    3
#define NUM_COORDS  (G3 / 4)                 // 4,194,304 (= 1 << 22)
#define GRID_ELEMS  (CASCADES * G3)          // 50,331,648
#define BF_ELEMS    (GRID_ELEMS / 8)         // 6,291,456

// ext_vector types so __builtin_nontemporal_load/store accept them
typedef int      i4 __attribute__((ext_vector_type(4)));
typedef float    f4 __attribute__((ext_vector_type(4)));
typedef uint32_t u4 __attribute__((ext_vector_type(4)));

__device__ __forceinline__ uint32_t part1by2(uint32_t x) {
    x &= 0x3FFu;
    x = (x | (x << 16)) & 0x030000FFu;
    x = (x | (x << 8))  & 0x0300F00Fu;
    x = (x | (x << 4))  & 0x030C30C3u;
    x = (x | (x << 2))  & 0x09249249u;
    return x;
}

// Pass 1 (per cascade): zero the 64 MB tag region (staged in-place in d_out).
// Plain (cached) stores: the implicit release at kernel end pushes these to
// L3, where the scatter atomics want them resident.
__global__ void clear_tags(u4* __restrict__ tags) {
    int t = blockIdx.x * blockDim.x + threadIdx.x;   // [0, G3/4)
    u4 z = {0u, 0u, 0u, 0u};
    tags[t] = z;
}

// Pass 2 (per cascade): last-write-wins scatter via order-priority
// atomicMax(tag = n+1). Each thread handles 4 coords (3 x int4 = 48 B,
// coalesced). Coords are read-once -> nontemporal, so the stream doesn't
// evict the hot 64 MB tag region from L3.
__global__ void scatter_tags(const i4* __restrict__ coords,
                             uint32_t* __restrict__ tags) {
    int t = blockIdx.x * blockDim.x + threadIdx.x;   // [0, NUM_COORDS/4)
    i4 a = __builtin_nontemporal_load(&coords[t * 3 + 0]);   // x0 y0 z0 x1
    i4 b = __builtin_nontemporal_load(&coords[t * 3 + 1]);   // y1 z1 x2 y2
    i4 c = __builtin_nontemporal_load(&coords[t * 3 + 2]);   // z2 x3 y3 z3

    uint32_t n0 = (uint32_t)(t * 4);

    uint32_t i0 = part1by2((uint32_t)a.x) | (part1by2((uint32_t)a.y) << 1) | (part1by2((uint32_t)a.z) << 2);
    uint32_t i1 = part1by2((uint32_t)a.w) | (part1by2((uint32_t)b.x) << 1) | (part1by2((uint32_t)b.y) << 2);
    uint32_t i2 = part1by2((uint32_t)b.z) | (part1by2((uint32_t)b.w) << 1) | (part1by2((uint32_t)c.x) << 2);
    uint32_t i3 = part1by2((uint32_t)c.y) | (part1by2((uint32_t)c.z) << 1) | (part1by2((uint32_t)c.w) << 2);

    atomicMax(&tags[i0], n0 + 1u);
    atomicMax(&tags[i1], n0 + 2u);
    atomicMax(&tags[i2], n0 + 3u);
    atomicMax(&tags[i3], n0 + 4u);
}

// Pass 3 (per cascade): in-place combine + bitfield. Each thread exclusively
// owns 8 cells (one bitfield byte), so reading tags then overwriting with
// floats is safe. Tag reads + sigma gather stay cached (both L3-hot per
// cascade: 64 MB + 17 MB); density stream and final stores are nontemporal.
__global__ void finalize(float* __restrict__ out,        // cascade grid base (== tag base)
                         float* __restrict__ bf,         // cascade bitfield base
                         const float* __restrict__ density,
                         const float* __restrict__ sig) {
    int t = blockIdx.x * blockDim.x + threadIdx.x;       // [0, G3/8)
    const u4* tg4 = (const u4*)out;
    u4 tg0 = tg4[t * 2 + 0];
    u4 tg1 = tg4[t * 2 + 1];
    f4 d0 = __builtin_nontemporal_load(&((const f4*)density)[t * 2 + 0]);
    f4 d1 = __builtin_nontemporal_load(&((const f4*)density)[t * 2 + 1]);

    uint32_t tg[8] = {tg0.x, tg0.y, tg0.z, tg0.w, tg1.x, tg1.y, tg1.z, tg1.w};
    float    dd[8] = {d0.x, d0.y, d0.z, d0.w, d1.x, d1.y, d1.z, d1.w};
    float    nv[8];
    uint32_t byte = 0u;

#pragma unroll
    for (int i = 0; i < 8; ++i) {
        float d = dd[i];
        float v = d;
        uint32_t tag = tg[i];
        if (tag != 0u) {
            float s = sig[tag - 1u];         // sigma * DENSITY_SCALE(=1.0)
            if (d >= 0.0f && s >= 0.0f) {    // valid = (old>=0) & (temp>=0)
                v = fmaxf(d * 0.95f, s);     // max(old*DECAY, temp)
            }
        }
        nv[i] = v;
        byte |= (v > 0.01f ? 1u : 0u) << i;  // bit b of byte = cell 8k+b
    }

    f4 o0 = {nv[0], nv[1], nv[2], nv[3]};
    f4 o1 = {nv[4], nv[5], nv[6], nv[7]};
    __builtin_nontemporal_store(o0, &((f4*)out)[t * 2 + 0]);
    __builtin_nontemporal_store(o1, &((f4*)out)[t * 2 + 1]);
    __builtin_nontemporal_store((float)byte, &bf[t]);    // bitfield byte as float32
}

extern "C" void kernel_launch(void* const* d_in, const int* in_sizes, int n_in,
                              void* d_out, int out_size, void* d_ws, size_t ws_size,
                              hipStream_t stream) {
    const float* density = (const float*)d_in[0];   // [3, 256^3] f32
    const float* sigmas  = (const float*)d_in[1];   // [3, 2^22]  f32
    const int*   coords  = (const int*)d_in[2];     // [3, 2^22, 3] i32
    float* out = (float*)d_out;                     // 50,331,648 grid + 6,291,456 bitfield floats

    // Cascade-chunked pipeline: keep each cascade's 64 MB tag region (plus its
    // 17 MB sigma table) resident in the 256 MB Infinity Cache across its
    // clear -> scatter -> finalize window, instead of thrashing L3 with the
    // full 201 MB tag grid + streams.
    for (int c = 0; c < CASCADES; ++c) {
        uint32_t* tg   = (uint32_t*)d_out + (size_t)c * G3;
        const int* cco = coords + (size_t)c * NUM_COORDS * 3;
        float*     og  = out + (size_t)c * G3;
        float*     ob  = out + GRID_ELEMS + (size_t)c * (G3 / 8);
        const float* dg = density + (size_t)c * G3;
        const float* sg = sigmas  + (size_t)c * NUM_COORDS;

        clear_tags  <<<G3 / 4 / 256,         256, 0, stream>>>((u4*)tg);
        scatter_tags<<<NUM_COORDS / 4 / 256, 256, 0, stream>>>((const i4*)cco, tg);
        finalize    <<<G3 / 8 / 256,         256, 0, stream>>>(og, ob, dg, sg);
    }
}

// Round 2
// 1093.519 us; speedup vs baseline: 1.0030x; 1.0030x over previous
//
#include <hip/hip_runtime.h>
#include <stdint.h>

#define G3          (256 * 256 * 256)        // 16,777,216 cells per cascade
#define CASCADES    3
#define NUM_COORDS  (G3 / 4)                 // 4,194,304 (= 1 << 22)
#define GRID_ELEMS  (CASCADES * G3)          // 50,331,648
#define BF_ELEMS    (GRID_ELEMS / 8)         // 6,291,456

// --- binning pipeline geometry ---
#define NBUK        16384                    // buckets per cascade; 1024 cells each
#define NB          512                      // coord-partition blocks (k_count/k_reorder)
#define CPB         (NUM_COORDS / NB)        // 8192 coords per block
#define GPB         (CPB / 4)                // 2048 groups-of-4 per block
#define K13_THREADS 512

typedef int      i4 __attribute__((ext_vector_type(4)));
typedef float    f4 __attribute__((ext_vector_type(4)));
typedef uint32_t u4 __attribute__((ext_vector_type(4)));

__device__ __forceinline__ uint32_t part1by2(uint32_t x) {
    x &= 0x3FFu;
    x = (x | (x << 16)) & 0x030000FFu;
    x = (x | (x << 8))  & 0x0300F00Fu;
    x = (x | (x << 4))  & 0x030C30C3u;
    x = (x | (x << 2))  & 0x09249249u;
    return x;
}

__device__ __forceinline__ void morton4(i4 a, i4 b, i4 c,
                                        uint32_t& m0, uint32_t& m1,
                                        uint32_t& m2, uint32_t& m3) {
    m0 = part1by2((uint32_t)a.x) | (part1by2((uint32_t)a.y) << 1) | (part1by2((uint32_t)a.z) << 2);
    m1 = part1by2((uint32_t)a.w) | (part1by2((uint32_t)b.x) << 1) | (part1by2((uint32_t)b.y) << 2);
    m2 = part1by2((uint32_t)b.z) | (part1by2((uint32_t)b.w) << 1) | (part1by2((uint32_t)c.x) << 2);
    m3 = part1by2((uint32_t)c.y) | (part1by2((uint32_t)c.z) << 1) | (part1by2((uint32_t)c.w) << 2);
}

// ====================== fast path: counting-sort binning ======================

// K1: per-block LDS histogram over 16384 Morton buckets -> hist[block][bucket].
__global__ __launch_bounds__(K13_THREADS) void k_count(const i4* __restrict__ coords,
                                                       uint32_t* __restrict__ hist) {
    __shared__ uint32_t h[NBUK];
    int tid = threadIdx.x;
    for (int j = tid; j < NBUK; j += K13_THREADS) h[j] = 0u;
    __syncthreads();

    int g0 = blockIdx.x * GPB;
#pragma unroll
    for (int it = 0; it < GPB / K13_THREADS; ++it) {
        int g = g0 + it * K13_THREADS + tid;
        i4 a = __builtin_nontemporal_load(&coords[g * 3 + 0]);
        i4 b = __builtin_nontemporal_load(&coords[g * 3 + 1]);
        i4 c = __builtin_nontemporal_load(&coords[g * 3 + 2]);
        uint32_t m0, m1, m2, m3;
        morton4(a, b, c, m0, m1, m2, m3);
        atomicAdd(&h[m0 >> 10], 1u);
        atomicAdd(&h[m1 >> 10], 1u);
        atomicAdd(&h[m2 >> 10], 1u);
        atomicAdd(&h[m3 >> 10], 1u);
    }
    __syncthreads();
    uint32_t* hrow = hist + (size_t)blockIdx.x * NBUK;
    for (int j = tid; j < NBUK; j += K13_THREADS) hrow[j] = h[j];
}

// K2a: within-group-of-8-partitions exclusive prefix; S[g][j] = group sum.
__global__ void k_sum8(uint32_t* __restrict__ hist, uint32_t* __restrict__ S) {
    int t = blockIdx.x * blockDim.x + threadIdx.x;   // [0, 64*NBUK)
    int g = t / NBUK;
    int j = t - g * NBUK;
    uint32_t run = 0;
#pragma unroll
    for (int k = 0; k < 8; ++k) {
        uint32_t* p = &hist[(size_t)(8 * g + k) * NBUK + j];
        uint32_t v = *p;
        *p = run;
        run += v;
    }
    S[(size_t)g * NBUK + j] = run;
}

// K2b: prefix over the 64 groups; total[j] = bucket total.
__global__ void k_sum64(uint32_t* __restrict__ S, uint32_t* __restrict__ total) {
    int j = blockIdx.x * blockDim.x + threadIdx.x;   // [0, NBUK)
    uint32_t run = 0;
#pragma unroll 8
    for (int g = 0; g < 64; ++g) {
        uint32_t* p = &S[(size_t)g * NBUK + j];
        uint32_t v = *p;
        *p = run;
        run += v;
    }
    total[j] = run;
}

// K2c: single-block exclusive scan of the 16384 bucket totals -> base[].
__global__ __launch_bounds__(1024) void k_scan(const uint32_t* __restrict__ total,
                                               uint32_t* __restrict__ base) {
    __shared__ uint32_t s[1024];
    int t = threadIdx.x;
    uint32_t loc[16];
    uint32_t sum = 0;
#pragma unroll
    for (int k = 0; k < 16; ++k) { loc[k] = total[t * 16 + k]; sum += loc[k]; }
    s[t] = sum;
    __syncthreads();
    for (int off = 1; off < 1024; off <<= 1) {
        uint32_t v = (t >= off) ? s[t - off] : 0u;
        __syncthreads();
        s[t] += v;
        __syncthreads();
    }
    uint32_t run = s[t] - sum;                       // exclusive prefix of this chunk
#pragma unroll
    for (int k = 0; k < 16; ++k) { base[t * 16 + k] = run; run += loc[k]; }
}

// K3: place pairs. pair = [local_cell:10 | prio(n):22 | sigma_bits:32].
// Slots reserved via LDS cursors seeded from base + S + hist -> zero global atomics.
__global__ __launch_bounds__(K13_THREADS) void k_reorder(const i4* __restrict__ coords,
                                                         const f4* __restrict__ sig4,
                                                         const uint32_t* __restrict__ hist,
                                                         const uint32_t* __restrict__ S,
                                                         const uint32_t* __restrict__ base,
                                                         unsigned long long* __restrict__ pairs) {
    __shared__ uint32_t cur[NBUK];
    int tid = threadIdx.x;
    const uint32_t* hrow = hist + (size_t)blockIdx.x * NBUK;
    const uint32_t* srow = S + (size_t)(blockIdx.x >> 3) * NBUK;
    for (int j = tid; j < NBUK; j += K13_THREADS)
        cur[j] = base[j] + srow[j] + hrow[j];
    __syncthreads();

    int g0 = blockIdx.x * GPB;
#pragma unroll
    for (int it = 0; it < GPB / K13_THREADS; ++it) {
        int g = g0 + it * K13_THREADS + tid;
        i4 a = __builtin_nontemporal_load(&coords[g * 3 + 0]);
        i4 b = __builtin_nontemporal_load(&coords[g * 3 + 1]);
        i4 c = __builtin_nontemporal_load(&coords[g * 3 + 2]);
        f4 sg = __builtin_nontemporal_load(&sig4[g]);
        uint32_t m0, m1, m2, m3;
        morton4(a, b, c, m0, m1, m2, m3);
        uint32_t n0 = (uint32_t)g * 4u;

        uint32_t s0 = atomicAdd(&cur[m0 >> 10], 1u);
        unsigned long long p0 = ((unsigned long long)(m0 & 1023u) << 54) |
                                ((unsigned long long)(n0 + 0u) << 32) | (uint32_t)__float_as_uint(sg.x);
        __builtin_nontemporal_store(p0, &pairs[s0]);

        uint32_t s1 = atomicAdd(&cur[m1 >> 10], 1u);
        unsigned long long p1 = ((unsigned long long)(m1 & 1023u) << 54) |
                                ((unsigned long long)(n0 + 1u) << 32) | (uint32_t)__float_as_uint(sg.y);
        __builtin_nontemporal_store(p1, &pairs[s1]);

        uint32_t s2 = atomicAdd(&cur[m2 >> 10], 1u);
        unsigned long long p2 = ((unsigned long long)(m2 & 1023u) << 54) |
                                ((unsigned long long)(n0 + 2u) << 32) | (uint32_t)__float_as_uint(sg.z);
        __builtin_nontemporal_store(p2, &pairs[s2]);

        uint32_t s3 = atomicAdd(&cur[m3 >> 10], 1u);
        unsigned long long p3 = ((unsigned long long)(m3 & 1023u) << 54) |
                                ((unsigned long long)(n0 + 3u) << 32) | (uint32_t)__float_as_uint(sg.w);
        __builtin_nontemporal_store(p3, &pairs[s3]);
    }
}

// K4: one block per bucket. LDS u64 atomicMax((prio+1)<<32 | sigma) resolves
// last-write-wins per cell; fused decay/max combine + bitfield, all coalesced.
__global__ __launch_bounds__(256) void k_final(const unsigned long long* __restrict__ pairs,
                                               const uint32_t* __restrict__ base,
                                               const uint32_t* __restrict__ total,
                                               const f4* __restrict__ density4,
                                               f4* __restrict__ out4,
                                               float* __restrict__ bf) {
    __shared__ unsigned long long tag[1024];
    __shared__ uint32_t bytebits[128];
    int b = blockIdx.x, tid = threadIdx.x;
    for (int k = tid; k < 1024; k += 256) tag[k] = 0ull;
    if (tid < 128) bytebits[tid] = 0u;
    __syncthreads();

    uint32_t s = base[b];
    uint32_t n = total[b];
    for (uint32_t i = (uint32_t)tid; i < n; i += 256u) {
        unsigned long long p = pairs[s + i];
        int local = (int)(p >> 54);
        unsigned long long val = (p & 0x003FFFFFFFFFFFFFull) + (1ull << 32);
        atomicMax(&tag[local], val);
    }
    __syncthreads();

    int c4 = b * 256 + tid;                          // index in 4-cell units
    f4 d = __builtin_nontemporal_load(&density4[c4]);
    f4 o;
    uint32_t nib = 0u;
#pragma unroll
    for (int k = 0; k < 4; ++k) {
        float v = d[k];
        unsigned long long tg = tag[tid * 4 + k];
        if (tg != 0ull) {
            float sgm = __uint_as_float((uint32_t)tg);
            if (v >= 0.0f && sgm >= 0.0f) v = fmaxf(v * 0.95f, sgm);
        }
        o[k] = v;
        nib |= (v > 0.01f ? 1u : 0u) << k;
    }
    __builtin_nontemporal_store(o, &out4[c4]);
    atomicOr(&bytebits[tid >> 1], nib << ((tid & 1) * 4));
    __syncthreads();
    if (tid < 128)
        __builtin_nontemporal_store((float)bytebits[tid], &bf[b * 128 + tid]);
}

// ================= fallback path (round-1 verified atomic scatter) =================

__global__ void clear_tags(u4* __restrict__ tags) {
    int t = blockIdx.x * blockDim.x + threadIdx.x;
    u4 z = {0u, 0u, 0u, 0u};
    tags[t] = z;
}

__global__ void scatter_tags(const i4* __restrict__ coords,
                             uint32_t* __restrict__ tags) {
    int t = blockIdx.x * blockDim.x + threadIdx.x;
    i4 a = __builtin_nontemporal_load(&coords[t * 3 + 0]);
    i4 b = __builtin_nontemporal_load(&coords[t * 3 + 1]);
    i4 c = __builtin_nontemporal_load(&coords[t * 3 + 2]);
    uint32_t n0 = (uint32_t)(t * 4);
    uint32_t m0, m1, m2, m3;
    morton4(a, b, c, m0, m1, m2, m3);
    atomicMax(&tags[m0], n0 + 1u);
    atomicMax(&tags[m1], n0 + 2u);
    atomicMax(&tags[m2], n0 + 3u);
    atomicMax(&tags[m3], n0 + 4u);
}

__global__ void finalize(float* __restrict__ out, float* __restrict__ bf,
                         const float* __restrict__ density,
                         const float* __restrict__ sig) {
    int t = blockIdx.x * blockDim.x + threadIdx.x;
    const u4* tg4 = (const u4*)out;
    u4 tg0 = tg4[t * 2 + 0];
    u4 tg1 = tg4[t * 2 + 1];
    f4 d0 = __builtin_nontemporal_load(&((const f4*)density)[t * 2 + 0]);
    f4 d1 = __builtin_nontemporal_load(&((const f4*)density)[t * 2 + 1]);

    uint32_t tg[8] = {tg0.x, tg0.y, tg0.z, tg0.w, tg1.x, tg1.y, tg1.z, tg1.w};
    float    dd[8] = {d0.x, d0.y, d0.z, d0.w, d1.x, d1.y, d1.z, d1.w};
    float    nv[8];
    uint32_t byte = 0u;
#pragma unroll
    for (int i = 0; i < 8; ++i) {
        float d = dd[i];
        float v = d;
        uint32_t tag = tg[i];
        if (tag != 0u) {
            float s = sig[tag - 1u];
            if (d >= 0.0f && s >= 0.0f) v = fmaxf(d * 0.95f, s);
        }
        nv[i] = v;
        byte |= (v > 0.01f ? 1u : 0u) << i;
    }
    f4 o0 = {nv[0], nv[1], nv[2], nv[3]};
    f4 o1 = {nv[4], nv[5], nv[6], nv[7]};
    __builtin_nontemporal_store(o0, &((f4*)out)[t * 2 + 0]);
    __builtin_nontemporal_store(o1, &((f4*)out)[t * 2 + 1]);
    __builtin_nontemporal_store((float)byte, &bf[t]);
}

// ==================================================================================

extern "C" void kernel_launch(void* const* d_in, const int* in_sizes, int n_in,
                              void* d_out, int out_size, void* d_ws, size_t ws_size,
                              hipStream_t stream) {
    const float* density = (const float*)d_in[0];   // [3, 256^3] f32
    const float* sigmas  = (const float*)d_in[1];   // [3, 2^22]  f32
    const int*   coords  = (const int*)d_in[2];     // [3, 2^22, 3] i32
    float* out = (float*)d_out;

    // workspace layout: pairs 32MB | hist 32MB | S 4MB | base 64KB | total 64KB
    const size_t OFF_HIST  = 33554432ull;
    const size_t OFF_S     = OFF_HIST + 33554432ull;
    const size_t OFF_BASE  = OFF_S + 4194304ull;
    const size_t OFF_TOTAL = OFF_BASE + 65536ull;
    const size_t NEED      = OFF_TOTAL + 65536ull;   // 71,434,240 B

    if (d_ws != nullptr && ws_size >= NEED) {
        char* w = (char*)d_ws;
        unsigned long long* pairs = (unsigned long long*)w;
        uint32_t* hist  = (uint32_t*)(w + OFF_HIST);
        uint32_t* S     = (uint32_t*)(w + OFF_S);
        uint32_t* base  = (uint32_t*)(w + OFF_BASE);
        uint32_t* total = (uint32_t*)(w + OFF_TOTAL);

        for (int c = 0; c < CASCADES; ++c) {
            const i4* cco = (const i4*)(coords + (size_t)c * NUM_COORDS * 3);
            const f4* sg4 = (const f4*)(sigmas + (size_t)c * NUM_COORDS);
            const f4* dg4 = (const f4*)(density + (size_t)c * G3);
            f4*       og4 = (f4*)(out + (size_t)c * G3);
            float*    ob  = out + GRID_ELEMS + (size_t)c * (G3 / 8);

            k_count  <<<NB, K13_THREADS, 0, stream>>>(cco, hist);
            k_sum8   <<<(64 * NBUK) / 256, 256, 0, stream>>>(hist, S);
            k_sum64  <<<NBUK / 256, 256, 0, stream>>>(S, total);
            k_scan   <<<1, 1024, 0, stream>>>(total, base);
            k_reorder<<<NB, K13_THREADS, 0, stream>>>(cco, sg4, hist, S, base, pairs);
            k_final  <<<NBUK, 256, 0, stream>>>(pairs, base, total, dg4, og4, ob);
        }
    } else {
        // fallback: round-1 verified cascade-chunked atomic path
        for (int c = 0; c < CASCADES; ++c) {
            uint32_t* tg   = (uint32_t*)d_out + (size_t)c * G3;
            const int* cco = coords + (size_t)c * NUM_COORDS * 3;
            float*     og  = out + (size_t)c * G3;
            float*     ob  = out + GRID_ELEMS + (size_t)c * (G3 / 8);
            const float* dg = density + (size_t)c * G3;
            const float* sg = sigmas  + (size_t)c * NUM_COORDS;

            clear_tags  <<<G3 / 4 / 256,         256, 0, stream>>>((u4*)tg);
            scatter_tags<<<NUM_COORDS / 4 / 256, 256, 0, stream>>>((const i4*)cco, tg);
            finalize    <<<G3 / 8 / 256,         256, 0, stream>>>(og, ob, dg, sg);
        }
    }
}

// Round 4
// 1048.505 us; speedup vs baseline: 1.0460x; 1.0429x over previous
//
#include <hip/hip_runtime.h>
#include <stdint.h>

#define G3          (256 * 256 * 256)        // 16,777,216 cells per cascade
#define CASCADES    3
#define NUM_COORDS  (G3 / 4)                 // 4,194,304 (= 1 << 22)
#define GRID_ELEMS  (CASCADES * G3)          // 50,331,648
#define BF_ELEMS    (GRID_ELEMS / 8)         // 6,291,456

// --- binning geometry ---
#define NBUK        2048                     // buckets; 8192 cells each (morton >> 13)
#define BCELLS      8192                     // cells per bucket
#define NB          256                      // coord-partition blocks
#define CPB         (NUM_COORDS / NB)        // 16384 coords per block
#define GPB         (CPB / 4)                // 4096 groups-of-4 per block
#define KTHREADS    512

typedef int       i4  __attribute__((ext_vector_type(4)));
typedef float     f4  __attribute__((ext_vector_type(4)));
typedef float     f2  __attribute__((ext_vector_type(2)));
typedef uint32_t  u4  __attribute__((ext_vector_type(4)));
typedef unsigned long long ull;
typedef ull       ull2 __attribute__((ext_vector_type(2)));

__device__ __forceinline__ uint32_t part1by2(uint32_t x) {
    x &= 0x3FFu;
    x = (x | (x << 16)) & 0x030000FFu;
    x = (x | (x << 8))  & 0x0300F00Fu;
    x = (x | (x << 4))  & 0x030C30C3u;
    x = (x | (x << 2))  & 0x09249249u;
    return x;
}

__device__ __forceinline__ void morton4(i4 a, i4 b, i4 c,
                                        uint32_t& m0, uint32_t& m1,
                                        uint32_t& m2, uint32_t& m3) {
    m0 = part1by2((uint32_t)a.x) | (part1by2((uint32_t)a.y) << 1) | (part1by2((uint32_t)a.z) << 2);
    m1 = part1by2((uint32_t)a.w) | (part1by2((uint32_t)b.x) << 1) | (part1by2((uint32_t)b.y) << 2);
    m2 = part1by2((uint32_t)b.z) | (part1by2((uint32_t)b.w) << 1) | (part1by2((uint32_t)c.x) << 2);
    m3 = part1by2((uint32_t)c.y) | (part1by2((uint32_t)c.z) << 1) | (part1by2((uint32_t)c.w) << 2);
}

// LDS tag-array bank-conflict swizzle: bijective, injects high bits into low nibble
__device__ __forceinline__ int swz(int i) { return i ^ ((i >> 4) & 15); }

// ====================== fast path: counting-sort binning ======================

// K1: per-block LDS histogram over 2048 buckets -> hist[block][bucket]. Coords
// loads are CACHED so the 48 MB stream stays L3-resident for k_reorder's re-read.
__global__ __launch_bounds__(KTHREADS) void k_count(const i4* __restrict__ coords,
                                                    uint32_t* __restrict__ hist) {
    __shared__ uint32_t h[NBUK];
    int tid = threadIdx.x;
    for (int j = tid; j < NBUK; j += KTHREADS) h[j] = 0u;
    __syncthreads();

    int g0 = blockIdx.x * GPB;
#pragma unroll
    for (int it = 0; it < GPB / KTHREADS; ++it) {
        int g = g0 + it * KTHREADS + tid;
        i4 a = coords[g * 3 + 0];
        i4 b = coords[g * 3 + 1];
        i4 c = coords[g * 3 + 2];
        uint32_t m0, m1, m2, m3;
        morton4(a, b, c, m0, m1, m2, m3);
        atomicAdd(&h[m0 >> 13], 1u);
        atomicAdd(&h[m1 >> 13], 1u);
        atomicAdd(&h[m2 >> 13], 1u);
        atomicAdd(&h[m3 >> 13], 1u);
    }
    __syncthreads();
    uint32_t* hrow = hist + (size_t)blockIdx.x * NBUK;
    for (int j = tid; j < NBUK; j += KTHREADS) hrow[j] = h[j];
}

// K2a: exclusive prefix within groups of 8 partition rows; S[g][j] = group sum.
__global__ __launch_bounds__(512) void k_sumA(uint32_t* __restrict__ hist,
                                              uint32_t* __restrict__ S) {
    int t = blockIdx.x * blockDim.x + threadIdx.x;   // [0, 32*NBUK)
    int g = t >> 11;
    int j = t & (NBUK - 1);
    uint32_t run = 0;
#pragma unroll
    for (int k = 0; k < 8; ++k) {
        uint32_t* p = &hist[(size_t)(8 * g + k) * NBUK + j];
        uint32_t v = *p;
        *p = run;
        run += v;
    }
    S[(size_t)g * NBUK + j] = run;
}

// K2b: exclusive prefix over the 32 groups; total[j] = bucket total.
__global__ __launch_bounds__(256) void k_sumB(uint32_t* __restrict__ S,
                                              uint32_t* __restrict__ total) {
    int j = blockIdx.x * blockDim.x + threadIdx.x;   // [0, NBUK)
    uint32_t run = 0;
#pragma unroll 8
    for (int g = 0; g < 32; ++g) {
        uint32_t* p = &S[(size_t)g * NBUK + j];
        uint32_t v = *p;
        *p = run;
        run += v;
    }
    total[j] = run;
}

// K2c: single-block exclusive scan of 2048 bucket totals -> base[] (pair slots).
__global__ __launch_bounds__(1024) void k_scan(const uint32_t* __restrict__ total,
                                               uint32_t* __restrict__ base) {
    __shared__ uint32_t s[1024];
    int t = threadIdx.x;
    uint32_t l0 = total[2 * t], l1 = total[2 * t + 1];
    uint32_t sum = l0 + l1;
    s[t] = sum;
    __syncthreads();
    for (int off = 1; off < 1024; off <<= 1) {
        uint32_t v = (t >= off) ? s[t - off] : 0u;
        __syncthreads();
        s[t] += v;
        __syncthreads();
    }
    uint32_t run = s[t] - sum;
    base[2 * t]     = run;
    base[2 * t + 1] = run + l0;
}

// K3: place 16B pairs {val = (n+1)<<32 | sigma_bits, local cell}. Slots come from
// LDS cursors seeded by base+S+hist. Stores are CACHED: each block writes ~8
// consecutive slots per bucket (128 B runs), so L2 write-allocate merges them
// into full-line writebacks instead of 4.19M independent 32 B sector writes.
__global__ __launch_bounds__(KTHREADS) void k_reorder(const i4* __restrict__ coords,
                                                      const f4* __restrict__ sig4,
                                                      const uint32_t* __restrict__ hist,
                                                      const uint32_t* __restrict__ S,
                                                      const uint32_t* __restrict__ base,
                                                      ull2* __restrict__ pairs) {
    __shared__ uint32_t cur[NBUK];
    int tid = threadIdx.x;
    const uint32_t* hrow = hist + (size_t)blockIdx.x * NBUK;
    const uint32_t* srow = S + (size_t)(blockIdx.x >> 3) * NBUK;
    for (int j = tid; j < NBUK; j += KTHREADS)
        cur[j] = base[j] + srow[j] + hrow[j];
    __syncthreads();

    int g0 = blockIdx.x * GPB;
#pragma unroll
    for (int it = 0; it < GPB / KTHREADS; ++it) {
        int g = g0 + it * KTHREADS + tid;
        i4 a = coords[g * 3 + 0];
        i4 b = coords[g * 3 + 1];
        i4 c = coords[g * 3 + 2];
        f4 sg = __builtin_nontemporal_load(&sig4[g]);
        uint32_t m0, m1, m2, m3;
        morton4(a, b, c, m0, m1, m2, m3);
        ull n1 = (ull)((uint32_t)g * 4u + 1u);

        uint32_t s0 = atomicAdd(&cur[m0 >> 13], 1u);
        pairs[s0] = (ull2){((n1 + 0) << 32) | (uint32_t)__float_as_uint(sg.x), (ull)(m0 & 8191u)};
        uint32_t s1 = atomicAdd(&cur[m1 >> 13], 1u);
        pairs[s1] = (ull2){((n1 + 1) << 32) | (uint32_t)__float_as_uint(sg.y), (ull)(m1 & 8191u)};
        uint32_t s2 = atomicAdd(&cur[m2 >> 13], 1u);
        pairs[s2] = (ull2){((n1 + 2) << 32) | (uint32_t)__float_as_uint(sg.z), (ull)(m2 & 8191u)};
        uint32_t s3 = atomicAdd(&cur[m3 >> 13], 1u);
        pairs[s3] = (ull2){((n1 + 3) << 32) | (uint32_t)__float_as_uint(sg.w), (ull)(m3 & 8191u)};
    }
}

// K4: one block per 8192-cell bucket. LDS u64 atomicMax resolves last-write-wins
// (high bits = n+1, unique per pair); fused decay/max + bitfield, all coalesced.
// Tag indices XOR-swizzled to break the stride-128B bank conflict on reads.
__global__ __launch_bounds__(KTHREADS) void k_final(const ull2* __restrict__ pairs,
                                                    const uint32_t* __restrict__ base,
                                                    const uint32_t* __restrict__ total,
                                                    const f4* __restrict__ density4,
                                                    f4* __restrict__ out4,
                                                    f2* __restrict__ bf2) {
    __shared__ ull tag[BCELLS];               // 64 KB -> 2 blocks/CU
    int b = blockIdx.x, tid = threadIdx.x;
    for (int i = tid; i < BCELLS; i += KTHREADS) tag[i] = 0ull;
    __syncthreads();

    uint32_t s = base[b];
    uint32_t n = total[b];
    for (uint32_t i = (uint32_t)tid; i < n; i += (uint32_t)KTHREADS) {
        ull2 p = pairs[s + i];
        atomicMax(&tag[swz((int)(uint32_t)p.y)], p.x);
    }
    __syncthreads();

    int f0 = b * (BCELLS / 4) + tid * 4;      // f4 index of this thread's 16 cells
    uint32_t by0 = 0u, by1 = 0u;
#pragma unroll
    for (int q = 0; q < 4; ++q) {
        f4 d = __builtin_nontemporal_load(&density4[f0 + q]);
        f4 o;
#pragma unroll
        for (int k = 0; k < 4; ++k) {
            int cell = tid * 16 + q * 4 + k;
            ull tg = tag[swz(cell)];
            float v = d[k];
            if (tg != 0ull) {
                float sgm = __uint_as_float((uint32_t)tg);
                if (v >= 0.0f && sgm >= 0.0f) v = fmaxf(v * 0.95f, sgm);
            }
            o[k] = v;
            uint32_t bit = (v > 0.01f) ? 1u : 0u;
            if (q < 2) by0 |= bit << (q * 4 + k);
            else       by1 |= bit << ((q - 2) * 4 + k);
        }
        __builtin_nontemporal_store(o, &out4[f0 + q]);
    }
    f2 bo = {(float)by0, (float)by1};
    __builtin_nontemporal_store(bo, &bf2[b * (BCELLS / 16) + tid]);
}

// ================= fallback path (round-1 verified atomic scatter) =================

__global__ void clear_tags(u4* __restrict__ tags) {
    int t = blockIdx.x * blockDim.x + threadIdx.x;
    u4 z = {0u, 0u, 0u, 0u};
    tags[t] = z;
}

__global__ void scatter_tags(const i4* __restrict__ coords,
                             uint32_t* __restrict__ tags) {
    int t = blockIdx.x * blockDim.x + threadIdx.x;
    i4 a = __builtin_nontemporal_load(&coords[t * 3 + 0]);
    i4 b = __builtin_nontemporal_load(&coords[t * 3 + 1]);
    i4 c = __builtin_nontemporal_load(&coords[t * 3 + 2]);
    uint32_t n0 = (uint32_t)(t * 4);
    uint32_t m0, m1, m2, m3;
    morton4(a, b, c, m0, m1, m2, m3);
    atomicMax(&tags[m0], n0 + 1u);
    atomicMax(&tags[m1], n0 + 2u);
    atomicMax(&tags[m2], n0 + 3u);
    atomicMax(&tags[m3], n0 + 4u);
}

__global__ void finalize(float* __restrict__ out, float* __restrict__ bf,
                         const float* __restrict__ density,
                         const float* __restrict__ sig) {
    int t = blockIdx.x * blockDim.x + threadIdx.x;
    const u4* tg4 = (const u4*)out;
    u4 tg0 = tg4[t * 2 + 0];
    u4 tg1 = tg4[t * 2 + 1];
    f4 d0 = __builtin_nontemporal_load(&((const f4*)density)[t * 2 + 0]);
    f4 d1 = __builtin_nontemporal_load(&((const f4*)density)[t * 2 + 1]);

    uint32_t tg[8] = {tg0.x, tg0.y, tg0.z, tg0.w, tg1.x, tg1.y, tg1.z, tg1.w};
    float    dd[8] = {d0.x, d0.y, d0.z, d0.w, d1.x, d1.y, d1.z, d1.w};
    float    nv[8];
    uint32_t byte = 0u;
#pragma unroll
    for (int i = 0; i < 8; ++i) {
        float d = dd[i];
        float v = d;
        uint32_t tag = tg[i];
        if (tag != 0u) {
            float s = sig[tag - 1u];
            if (d >= 0.0f && s >= 0.0f) v = fmaxf(d * 0.95f, s);
        }
        nv[i] = v;
        byte |= (v > 0.01f ? 1u : 0u) << i;
    }
    f4 o0 = {nv[0], nv[1], nv[2], nv[3]};
    f4 o1 = {nv[4], nv[5], nv[6], nv[7]};
    __builtin_nontemporal_store(o0, &((f4*)out)[t * 2 + 0]);
    __builtin_nontemporal_store(o1, &((f4*)out)[t * 2 + 1]);
    __builtin_nontemporal_store((float)byte, &bf[t]);
}

// ==================================================================================

extern "C" void kernel_launch(void* const* d_in, const int* in_sizes, int n_in,
                              void* d_out, int out_size, void* d_ws, size_t ws_size,
                              hipStream_t stream) {
    const float* density = (const float*)d_in[0];   // [3, 256^3] f32
    const float* sigmas  = (const float*)d_in[1];   // [3, 2^22]  f32
    const int*   coords  = (const int*)d_in[2];     // [3, 2^22, 3] i32
    float* out = (float*)d_out;

    // workspace: pairs 64MB | hist 2MB | S 256KB | base 8KB | total 8KB
    const size_t OFF_HIST  = (size_t)NUM_COORDS * 16ull;          // 67,108,864
    const size_t OFF_S     = OFF_HIST + (size_t)NB * NBUK * 4ull; // + 2 MB
    const size_t OFF_BASE  = OFF_S + 32ull * NBUK * 4ull;         // + 256 KB
    const size_t OFF_TOTAL = OFF_BASE + NBUK * 4ull;
    const size_t NEED      = OFF_TOTAL + NBUK * 4ull;             // ~69.5 MB

    if (d_ws != nullptr && ws_size >= NEED) {
        char* w = (char*)d_ws;
        ull2*     pairs = (ull2*)w;
        uint32_t* hist  = (uint32_t*)(w + OFF_HIST);
        uint32_t* S     = (uint32_t*)(w + OFF_S);
        uint32_t* base  = (uint32_t*)(w + OFF_BASE);
        uint32_t* total = (uint32_t*)(w + OFF_TOTAL);

        for (int c = 0; c < CASCADES; ++c) {
            const i4* cco = (const i4*)(coords + (size_t)c * NUM_COORDS * 3);
            const f4* sg4 = (const f4*)(sigmas + (size_t)c * NUM_COORDS);
            const f4* dg4 = (const f4*)(density + (size_t)c * G3);
            f4*       og4 = (f4*)(out + (size_t)c * G3);
            f2*       ob2 = (f2*)(out + GRID_ELEMS + (size_t)c * (G3 / 8));

            k_count  <<<NB, KTHREADS, 0, stream>>>(cco, hist);
            k_sumA   <<<(32 * NBUK) / 512, 512, 0, stream>>>(hist, S);
            k_sumB   <<<NBUK / 256, 256, 0, stream>>>(S, total);
            k_scan   <<<1, 1024, 0, stream>>>(total, base);
            k_reorder<<<NB, KTHREADS, 0, stream>>>(cco, sg4, hist, S, base, pairs);
            k_final  <<<NBUK, KTHREADS, 0, stream>>>(pairs, base, total, dg4, og4, ob2);
        }
    } else {
        // fallback: round-1 verified cascade-chunked atomic path
        for (int c = 0; c < CASCADES; ++c) {
            uint32_t* tg   = (uint32_t*)d_out + (size_t)c * G3;
            const int* cco = coords + (size_t)c * NUM_COORDS * 3;
            float*     og  = out + (size_t)c * G3;
            float*     ob  = out + GRID_ELEMS + (size_t)c * (G3 / 8);
            const float* dg = density + (size_t)c * G3;
            const float* sg = sigmas  + (size_t)c * NUM_COORDS;

            clear_tags  <<<G3 / 4 / 256,         256, 0, stream>>>((u4*)tg);
            scatter_tags<<<NUM_COORDS / 4 / 256, 256, 0, stream>>>((const i4*)cco, tg);
            finalize    <<<G3 / 8 / 256,         256, 0, stream>>>(og, ob, dg, sg);
        }
    }
}

// Round 5
// 768.079 us; speedup vs baseline: 1.4279x; 1.3651x over previous
//
#include <hip/hip_runtime.h>
#include <stdint.h>

#define G3          (256 * 256 * 256)        // 16,777,216 cells per cascade
#define CASCADES    3
#define NUM_COORDS  (G3 / 4)                 // 4,194,304 (= 1 << 22)
#define GRID_ELEMS  (CASCADES * G3)          // 50,331,648
#define BF_ELEMS    (GRID_ELEMS / 8)         // 6,291,456

// --- binning geometry ---
#define NBUK        2048                     // buckets; 8192 cells each (morton >> 13)
#define BCELLS      8192                     // cells per bucket
#define NB          256                      // coord-partition blocks
#define CPB         (NUM_COORDS / NB)        // 16384 coords per block
#define GPB         (CPB / 4)                // 4096 groups-of-4 per block
#define KTHREADS    512

typedef int       i4  __attribute__((ext_vector_type(4)));
typedef float     f4  __attribute__((ext_vector_type(4)));
typedef uint32_t  u4  __attribute__((ext_vector_type(4)));
typedef unsigned long long ull;
typedef ull       ull2 __attribute__((ext_vector_type(2)));

__device__ __forceinline__ uint32_t part1by2(uint32_t x) {
    x &= 0x3FFu;
    x = (x | (x << 16)) & 0x030000FFu;
    x = (x | (x << 8))  & 0x0300F00Fu;
    x = (x | (x << 4))  & 0x030C30C3u;
    x = (x | (x << 2))  & 0x09249249u;
    return x;
}

__device__ __forceinline__ void morton4(i4 a, i4 b, i4 c,
                                        uint32_t& m0, uint32_t& m1,
                                        uint32_t& m2, uint32_t& m3) {
    m0 = part1by2((uint32_t)a.x) | (part1by2((uint32_t)a.y) << 1) | (part1by2((uint32_t)a.z) << 2);
    m1 = part1by2((uint32_t)a.w) | (part1by2((uint32_t)b.x) << 1) | (part1by2((uint32_t)b.y) << 2);
    m2 = part1by2((uint32_t)b.z) | (part1by2((uint32_t)b.w) << 1) | (part1by2((uint32_t)c.x) << 2);
    m3 = part1by2((uint32_t)c.y) | (part1by2((uint32_t)c.z) << 1) | (part1by2((uint32_t)c.w) << 2);
}

// LDS tag-array bank-conflict swizzle: bijective, injects high bits into low nibble
__device__ __forceinline__ int swz(int i) { return i ^ ((i >> 4) & 15); }

// ====================== fast path: counting-sort binning ======================

// K1: per-block LDS histogram over 2048 buckets -> hist[block][bucket]; also
// emits Morton codes (NT stream) so k_reorder reads 16 MB codes instead of
// re-reading 48 MB coords + redoing the bit-spread.
__global__ __launch_bounds__(KTHREADS) void k_count(const i4* __restrict__ coords,
                                                    uint32_t* __restrict__ hist,
                                                    u4* __restrict__ mort) {
    __shared__ uint32_t h[NBUK];
    int tid = threadIdx.x;
    for (int j = tid; j < NBUK; j += KTHREADS) h[j] = 0u;
    __syncthreads();

    int g0 = blockIdx.x * GPB;
#pragma unroll
    for (int it = 0; it < GPB / KTHREADS; ++it) {
        int g = g0 + it * KTHREADS + tid;
        i4 a = coords[g * 3 + 0];
        i4 b = coords[g * 3 + 1];
        i4 c = coords[g * 3 + 2];
        uint32_t m0, m1, m2, m3;
        morton4(a, b, c, m0, m1, m2, m3);
        u4 mv = {m0, m1, m2, m3};
        __builtin_nontemporal_store(mv, &mort[g]);
        atomicAdd(&h[m0 >> 13], 1u);
        atomicAdd(&h[m1 >> 13], 1u);
        atomicAdd(&h[m2 >> 13], 1u);
        atomicAdd(&h[m3 >> 13], 1u);
    }
    __syncthreads();
    uint32_t* hrow = hist + (size_t)blockIdx.x * NBUK;
    for (int j = tid; j < NBUK; j += KTHREADS) hrow[j] = h[j];
}

// K2a: exclusive prefix within groups of 8 partition rows; S[g][j] = group sum.
__global__ __launch_bounds__(512) void k_sumA(uint32_t* __restrict__ hist,
                                              uint32_t* __restrict__ S) {
    int t = blockIdx.x * blockDim.x + threadIdx.x;   // [0, 32*NBUK)
    int g = t >> 11;
    int j = t & (NBUK - 1);
    uint32_t run = 0;
#pragma unroll
    for (int k = 0; k < 8; ++k) {
        uint32_t* p = &hist[(size_t)(8 * g + k) * NBUK + j];
        uint32_t v = *p;
        *p = run;
        run += v;
    }
    S[(size_t)g * NBUK + j] = run;
}

// K2b: exclusive prefix over the 32 groups; total[j] = bucket total.
__global__ __launch_bounds__(256) void k_sumB(uint32_t* __restrict__ S,
                                              uint32_t* __restrict__ total) {
    int j = blockIdx.x * blockDim.x + threadIdx.x;   // [0, NBUK)
    uint32_t run = 0;
#pragma unroll 8
    for (int g = 0; g < 32; ++g) {
        uint32_t* p = &S[(size_t)g * NBUK + j];
        uint32_t v = *p;
        *p = run;
        run += v;
    }
    total[j] = run;
}

// K2c: single-block exclusive scan of 2048 bucket totals -> base[] (pair slots).
__global__ __launch_bounds__(1024) void k_scan(const uint32_t* __restrict__ total,
                                               uint32_t* __restrict__ base) {
    __shared__ uint32_t s[1024];
    int t = threadIdx.x;
    uint32_t l0 = total[2 * t], l1 = total[2 * t + 1];
    uint32_t sum = l0 + l1;
    s[t] = sum;
    __syncthreads();
    for (int off = 1; off < 1024; off <<= 1) {
        uint32_t v = (t >= off) ? s[t - off] : 0u;
        __syncthreads();
        s[t] += v;
        __syncthreads();
    }
    uint32_t run = s[t] - sum;
    base[2 * t]     = run;
    base[2 * t + 1] = run + l0;
}

// K3: place 16B pairs {val = (n+1)<<32 | sigma_bits, local cell}. Slots come from
// LDS cursors seeded by base+S+hist. Stores are CACHED: each block writes ~8
// consecutive slots per bucket (128 B runs) -> L2 merges into line writebacks.
__global__ __launch_bounds__(KTHREADS) void k_reorder(const u4* __restrict__ mort,
                                                      const f4* __restrict__ sig4,
                                                      const uint32_t* __restrict__ hist,
                                                      const uint32_t* __restrict__ S,
                                                      const uint32_t* __restrict__ base,
                                                      ull2* __restrict__ pairs) {
    __shared__ uint32_t cur[NBUK];
    int tid = threadIdx.x;
    const uint32_t* hrow = hist + (size_t)blockIdx.x * NBUK;
    const uint32_t* srow = S + (size_t)(blockIdx.x >> 3) * NBUK;
    for (int j = tid; j < NBUK; j += KTHREADS)
        cur[j] = base[j] + srow[j] + hrow[j];
    __syncthreads();

    int g0 = blockIdx.x * GPB;
#pragma unroll
    for (int it = 0; it < GPB / KTHREADS; ++it) {
        int g = g0 + it * KTHREADS + tid;
        u4 m = mort[g];                              // L3-hot (just written by k_count)
        f4 sg = __builtin_nontemporal_load(&sig4[g]);
        ull n1 = (ull)((uint32_t)g * 4u + 1u);

        uint32_t s0 = atomicAdd(&cur[m.x >> 13], 1u);
        pairs[s0] = (ull2){((n1 + 0) << 32) | (uint32_t)__float_as_uint(sg.x), (ull)(m.x & 8191u)};
        uint32_t s1 = atomicAdd(&cur[m.y >> 13], 1u);
        pairs[s1] = (ull2){((n1 + 1) << 32) | (uint32_t)__float_as_uint(sg.y), (ull)(m.y & 8191u)};
        uint32_t s2 = atomicAdd(&cur[m.z >> 13], 1u);
        pairs[s2] = (ull2){((n1 + 2) << 32) | (uint32_t)__float_as_uint(sg.z), (ull)(m.z & 8191u)};
        uint32_t s3 = atomicAdd(&cur[m.w >> 13], 1u);
        pairs[s3] = (ull2){((n1 + 3) << 32) | (uint32_t)__float_as_uint(sg.w), (ull)(m.w & 8191u)};
    }
}

// K4: one block per 8192-cell bucket. LDS u64 atomicMax resolves last-write-wins;
// epilogue is LANE-MAJOR (fi = q*512+tid): each wave instruction touches 1 KiB
// contiguous -> NT stores merge into full lines (fixes the 2x write
// amplification seen at round 4: WRITE_SIZE 150 MB for 75 MB of payload).
__global__ __launch_bounds__(KTHREADS) void k_final(const ull2* __restrict__ pairs,
                                                    const uint32_t* __restrict__ base,
                                                    const uint32_t* __restrict__ total,
                                                    const f4* __restrict__ density4,
                                                    f4* __restrict__ out4,
                                                    float* __restrict__ bf) {
    __shared__ ull tag[BCELLS];               // 64 KB -> 2 blocks/CU
    int b = blockIdx.x, tid = threadIdx.x;
    for (int i = tid; i < BCELLS; i += KTHREADS) tag[i] = 0ull;
    __syncthreads();

    uint32_t s = base[b];
    uint32_t n = total[b];
    for (uint32_t i = (uint32_t)tid; i < n; i += (uint32_t)KTHREADS) {
        ull2 p = pairs[s + i];
        atomicMax(&tag[swz((int)(uint32_t)p.y)], p.x);
    }
    __syncthreads();

    int fbase = b * (BCELLS / 4);             // 2048 f4 per bucket
#pragma unroll
    for (int q = 0; q < 4; ++q) {
        int fi = q * 512 + tid;               // lane-major f4 index within bucket
        f4 d = __builtin_nontemporal_load(&density4[fbase + fi]);
        f4 o;
        uint32_t nib = 0u;
#pragma unroll
        for (int k = 0; k < 4; ++k) {
            int cell = fi * 4 + k;
            ull tg = tag[swz(cell)];
            float v = d[k];
            if (tg != 0ull) {
                float sgm = __uint_as_float((uint32_t)tg);
                if (v >= 0.0f && sgm >= 0.0f) v = fmaxf(v * 0.95f, sgm);
            }
            o[k] = v;
            nib |= (v > 0.01f ? 1u : 0u) << k;
        }
        __builtin_nontemporal_store(o, &out4[fbase + fi]);
        // byte j = cells 8j..8j+7 spans an even/odd lane pair: combine nibbles
        uint32_t other = __shfl_xor(nib, 1);
        if ((tid & 1) == 0) {
            uint32_t byte = nib | (other << 4);   // even lane = bits 0-3, odd = 4-7
            __builtin_nontemporal_store((float)byte,
                                        &bf[b * (BCELLS / 8) + q * 256 + (tid >> 1)]);
        }
    }
}

// ================= fallback path (round-1 verified atomic scatter) =================

__global__ void clear_tags(u4* __restrict__ tags) {
    int t = blockIdx.x * blockDim.x + threadIdx.x;
    u4 z = {0u, 0u, 0u, 0u};
    tags[t] = z;
}

__global__ void scatter_tags(const i4* __restrict__ coords,
                             uint32_t* __restrict__ tags) {
    int t = blockIdx.x * blockDim.x + threadIdx.x;
    i4 a = __builtin_nontemporal_load(&coords[t * 3 + 0]);
    i4 b = __builtin_nontemporal_load(&coords[t * 3 + 1]);
    i4 c = __builtin_nontemporal_load(&coords[t * 3 + 2]);
    uint32_t n0 = (uint32_t)(t * 4);
    uint32_t m0, m1, m2, m3;
    morton4(a, b, c, m0, m1, m2, m3);
    atomicMax(&tags[m0], n0 + 1u);
    atomicMax(&tags[m1], n0 + 2u);
    atomicMax(&tags[m2], n0 + 3u);
    atomicMax(&tags[m3], n0 + 4u);
}

__global__ void finalize(float* __restrict__ out, float* __restrict__ bf,
                         const float* __restrict__ density,
                         const float* __restrict__ sig) {
    int t = blockIdx.x * blockDim.x + threadIdx.x;
    const u4* tg4 = (const u4*)out;
    u4 tg0 = tg4[t * 2 + 0];
    u4 tg1 = tg4[t * 2 + 1];
    f4 d0 = __builtin_nontemporal_load(&((const f4*)density)[t * 2 + 0]);
    f4 d1 = __builtin_nontemporal_load(&((const f4*)density)[t * 2 + 1]);

    uint32_t tg[8] = {tg0.x, tg0.y, tg0.z, tg0.w, tg1.x, tg1.y, tg1.z, tg1.w};
    float    dd[8] = {d0.x, d0.y, d0.z, d0.w, d1.x, d1.y, d1.z, d1.w};
    float    nv[8];
    uint32_t byte = 0u;
#pragma unroll
    for (int i = 0; i < 8; ++i) {
        float d = dd[i];
        float v = d;
        uint32_t tag = tg[i];
        if (tag != 0u) {
            float s = sig[tag - 1u];
            if (d >= 0.0f && s >= 0.0f) v = fmaxf(d * 0.95f, s);
        }
        nv[i] = v;
        byte |= (v > 0.01f ? 1u : 0u) << i;
    }
    f4 o0 = {nv[0], nv[1], nv[2], nv[3]};
    f4 o1 = {nv[4], nv[5], nv[6], nv[7]};
    __builtin_nontemporal_store(o0, &((f4*)out)[t * 2 + 0]);
    __builtin_nontemporal_store(o1, &((f4*)out)[t * 2 + 1]);
    __builtin_nontemporal_store((float)byte, &bf[t]);
}

// ==================================================================================

extern "C" void kernel_launch(void* const* d_in, const int* in_sizes, int n_in,
                              void* d_out, int out_size, void* d_ws, size_t ws_size,
                              hipStream_t stream) {
    const float* density = (const float*)d_in[0];   // [3, 256^3] f32
    const float* sigmas  = (const float*)d_in[1];   // [3, 2^22]  f32
    const int*   coords  = (const int*)d_in[2];     // [3, 2^22, 3] i32
    float* out = (float*)d_out;

    // workspace: pairs 64MB | hist 2MB | S 256KB | base 8KB | total 8KB | mort 16MB
    const size_t OFF_HIST  = (size_t)NUM_COORDS * 16ull;          // 67,108,864
    const size_t OFF_S     = OFF_HIST + (size_t)NB * NBUK * 4ull; // + 2 MB
    const size_t OFF_BASE  = OFF_S + 32ull * NBUK * 4ull;         // + 256 KB
    const size_t OFF_TOTAL = OFF_BASE + NBUK * 4ull;
    const size_t OFF_MORT  = OFF_TOTAL + NBUK * 4ull;
    const size_t NEED      = OFF_MORT + (size_t)NUM_COORDS * 4ull; // ~86 MB

    if (d_ws != nullptr && ws_size >= NEED) {
        char* w = (char*)d_ws;
        ull2*     pairs = (ull2*)w;
        uint32_t* hist  = (uint32_t*)(w + OFF_HIST);
        uint32_t* S     = (uint32_t*)(w + OFF_S);
        uint32_t* base  = (uint32_t*)(w + OFF_BASE);
        uint32_t* total = (uint32_t*)(w + OFF_TOTAL);
        u4*       mort  = (u4*)(w + OFF_MORT);

        for (int c = 0; c < CASCADES; ++c) {
            const i4* cco = (const i4*)(coords + (size_t)c * NUM_COORDS * 3);
            const f4* sg4 = (const f4*)(sigmas + (size_t)c * NUM_COORDS);
            const f4* dg4 = (const f4*)(density + (size_t)c * G3);
            f4*       og4 = (f4*)(out + (size_t)c * G3);
            float*    ob  = out + GRID_ELEMS + (size_t)c * (G3 / 8);

            k_count  <<<NB, KTHREADS, 0, stream>>>(cco, hist, mort);
            k_sumA   <<<(32 * NBUK) / 512, 512, 0, stream>>>(hist, S);
            k_sumB   <<<NBUK / 256, 256, 0, stream>>>(S, total);
            k_scan   <<<1, 1024, 0, stream>>>(total, base);
            k_reorder<<<NB, KTHREADS, 0, stream>>>(mort, sg4, hist, S, base, pairs);
            k_final  <<<NBUK, KTHREADS, 0, stream>>>(pairs, base, total, dg4, og4, ob);
        }
    } else {
        // fallback: round-1 verified cascade-chunked atomic path
        for (int c = 0; c < CASCADES; ++c) {
            uint32_t* tg   = (uint32_t*)d_out + (size_t)c * G3;
            const int* cco = coords + (size_t)c * NUM_COORDS * 3;
            float*     og  = out + (size_t)c * G3;
            float*     ob  = out + GRID_ELEMS + (size_t)c * (G3 / 8);
            const float* dg = density + (size_t)c * G3;
            const float* sg = sigmas  + (size_t)c * NUM_COORDS;

            clear_tags  <<<G3 / 4 / 256,         256, 0, stream>>>((u4*)tg);
            scatter_tags<<<NUM_COORDS / 4 / 256, 256, 0, stream>>>((const i4*)cco, tg);
            finalize    <<<G3 / 8 / 256,         256, 0, stream>>>(og, ob, dg, sg);
        }
    }
}

// Round 9
// 751.682 us; speedup vs baseline: 1.4591x; 1.0218x over previous
//
#include <hip/hip_runtime.h>
#include <stdint.h>

#define G3          (256 * 256 * 256)        // 16,777,216 cells per cascade
#define CASCADES    3
#define NUM_COORDS  (G3 / 4)                 // 4,194,304 (= 1 << 22)
#define GRID_ELEMS  (CASCADES * G3)          // 50,331,648
#define BF_ELEMS    (GRID_ELEMS / 8)         // 6,291,456

// --- binning geometry ---
#define NBUK        2048                     // buckets; 8192 cells each (morton >> 13)
#define BCELLS      8192                     // cells per bucket
#define NB          256                      // coord-partition blocks
#define CPB         (NUM_COORDS / NB)        // 16384 coords per block
#define GPB         (CPB / 4)                // 4096 groups-of-4 per block
#define KTHREADS    512
#define CAP         2500                     // slab capacity/bucket (mean 2048 + 10 sigma)

typedef int       i4  __attribute__((ext_vector_type(4)));
typedef float     f4  __attribute__((ext_vector_type(4)));
typedef uint32_t  u4  __attribute__((ext_vector_type(4)));
typedef unsigned long long ull;
typedef ull       ull2 __attribute__((ext_vector_type(2)));

__device__ __forceinline__ uint32_t part1by2(uint32_t x) {
    x &= 0x3FFu;
    x = (x | (x << 16)) & 0x030000FFu;
    x = (x | (x << 8))  & 0x0300F00Fu;
    x = (x | (x << 4))  & 0x030C30C3u;
    x = (x | (x << 2))  & 0x09249249u;
    return x;
}

__device__ __forceinline__ void morton4(i4 a, i4 b, i4 c,
                                        uint32_t& m0, uint32_t& m1,
                                        uint32_t& m2, uint32_t& m3) {
    m0 = part1by2((uint32_t)a.x) | (part1by2((uint32_t)a.y) << 1) | (part1by2((uint32_t)a.z) << 2);
    m1 = part1by2((uint32_t)a.w) | (part1by2((uint32_t)b.x) << 1) | (part1by2((uint32_t)b.y) << 2);
    m2 = part1by2((uint32_t)b.z) | (part1by2((uint32_t)b.w) << 1) | (part1by2((uint32_t)c.x) << 2);
    m3 = part1by2((uint32_t)c.y) | (part1by2((uint32_t)c.z) << 1) | (part1by2((uint32_t)c.w) << 2);
}

// LDS tag-array bank-conflict swizzle: bijective, injects high bits into low nibble
__device__ __forceinline__ int swz(int i) { return i ^ ((i >> 4) & 15); }

// ====================== fast path: fused fixed-capacity binning ======================

// K0: zero the 3 cascades' bucket counters (one tiny launch per iteration).
__global__ __launch_bounds__(512) void k_zero(uint32_t* __restrict__ p) {
    p[blockIdx.x * 512 + threadIdx.x] = 0u;
}

// K1 (fused count+reorder): phase 1 computes Morton codes (kept in 32 statically-
// indexed VGPRs) + LDS histogram; then ONE global atomicAdd per (block,bucket)
// reserves a sub-segment of the bucket's fixed slab (no scans, no mort array);
// phase 2 writes 16 B pairs {val = (n+1)<<32 | sigma_bits, local cell} via LDS
// cursors. Pair order within a bucket is irrelevant: priority is in the value.
__global__ __launch_bounds__(KTHREADS) void k_scatter(const i4* __restrict__ coords,
                                                      const f4* __restrict__ sig4,
                                                      uint32_t* __restrict__ gcnt,
                                                      ull2* __restrict__ pairs) {
    __shared__ uint32_t cur[NBUK];           // histogram, then absolute cursors
    int tid = threadIdx.x;
    for (int j = tid; j < NBUK; j += KTHREADS) cur[j] = 0u;
    __syncthreads();

    uint32_t mt[8][4];                       // 32 mortons, statically indexed
    int g0 = blockIdx.x * GPB;
#pragma unroll
    for (int it = 0; it < GPB / KTHREADS; ++it) {
        int g = g0 + it * KTHREADS + tid;
        i4 a = __builtin_nontemporal_load(&coords[g * 3 + 0]);
        i4 b = __builtin_nontemporal_load(&coords[g * 3 + 1]);
        i4 c = __builtin_nontemporal_load(&coords[g * 3 + 2]);
        morton4(a, b, c, mt[it][0], mt[it][1], mt[it][2], mt[it][3]);
        atomicAdd(&cur[mt[it][0] >> 13], 1u);
        atomicAdd(&cur[mt[it][1] >> 13], 1u);
        atomicAdd(&cur[mt[it][2] >> 13], 1u);
        atomicAdd(&cur[mt[it][3] >> 13], 1u);
    }
    __syncthreads();

    // reserve this block's sub-segment in each bucket's slab
    for (int j = tid; j < NBUK; j += KTHREADS) {
        uint32_t h = cur[j];
        uint32_t ofs = atomicAdd(&gcnt[j], h);
        cur[j] = (uint32_t)j * CAP + ofs;    // absolute cursor (each j owned by 1 thread)
    }
    __syncthreads();

#pragma unroll
    for (int it = 0; it < GPB / KTHREADS; ++it) {
        int g = g0 + it * KTHREADS + tid;
        f4 sg = __builtin_nontemporal_load(&sig4[g]);
        ull n1 = (ull)((uint32_t)g * 4u + 1u);
#pragma unroll
        for (int k = 0; k < 4; ++k) {
            uint32_t m = mt[it][k];
            uint32_t j = m >> 13;
            uint32_t s = atomicAdd(&cur[j], 1u);
            if (s < (j + 1u) * CAP)          // overflow guard (P ~ 1e-23)
                pairs[s] = (ull2){((n1 + (ull)k) << 32) | (ull)(uint32_t)__float_as_uint(sg[k]),
                                  (ull)(m & 8191u)};
        }
    }
}

// K2: one block per 8192-cell bucket. LDS u64 atomicMax resolves last-write-wins;
// lane-major epilogue (fi = q*512+tid): each wave instruction touches 1 KiB
// contiguous so NT loads/stores run at full line rate (round-5 verified).
__global__ __launch_bounds__(KTHREADS) void k_final(const ull2* __restrict__ pairs,
                                                    const uint32_t* __restrict__ gcnt,
                                                    const f4* __restrict__ density4,
                                                    f4* __restrict__ out4,
                                                    float* __restrict__ bf) {
    __shared__ ull tag[BCELLS];               // 64 KB -> 2 blocks/CU
    int b = blockIdx.x, tid = threadIdx.x;
    for (int i = tid; i < BCELLS; i += KTHREADS) tag[i] = 0ull;
    __syncthreads();

    uint32_t n = gcnt[b];
    if (n > CAP) n = CAP;
    uint32_t s = (uint32_t)b * CAP;
    for (uint32_t i = (uint32_t)tid; i < n; i += (uint32_t)KTHREADS) {
        ull2 p = pairs[s + i];
        atomicMax(&tag[swz((int)(uint32_t)p.y)], p.x);
    }
    __syncthreads();

    int fbase = b * (BCELLS / 4);             // 2048 f4 per bucket
#pragma unroll
    for (int q = 0; q < 4; ++q) {
        int fi = q * 512 + tid;               // lane-major f4 index within bucket
        f4 d = __builtin_nontemporal_load(&density4[fbase + fi]);
        f4 o;
        uint32_t nib = 0u;
#pragma unroll
        for (int k = 0; k < 4; ++k) {
            int cell = fi * 4 + k;
            ull tg = tag[swz(cell)];
            float v = d[k];
            if (tg != 0ull) {
                float sgm = __uint_as_float((uint32_t)tg);
                if (v >= 0.0f && sgm >= 0.0f) v = fmaxf(v * 0.95f, sgm);
            }
            o[k] = v;
            nib |= (v > 0.01f ? 1u : 0u) << k;
        }
        __builtin_nontemporal_store(o, &out4[fbase + fi]);
        uint32_t other = __shfl_xor(nib, 1);
        if ((tid & 1) == 0) {
            uint32_t byte = nib | (other << 4);   // even lane = bits 0-3, odd = 4-7
            __builtin_nontemporal_store((float)byte,
                                        &bf[b * (BCELLS / 8) + q * 256 + (tid >> 1)]);
        }
    }
}

// ================= fallback path (round-1 verified atomic scatter) =================

__global__ void clear_tags(u4* __restrict__ tags) {
    int t = blockIdx.x * blockDim.x + threadIdx.x;
    u4 z = {0u, 0u, 0u, 0u};
    tags[t] = z;
}

__global__ void scatter_tags(const i4* __restrict__ coords,
                             uint32_t* __restrict__ tags) {
    int t = blockIdx.x * blockDim.x + threadIdx.x;
    i4 a = __builtin_nontemporal_load(&coords[t * 3 + 0]);
    i4 b = __builtin_nontemporal_load(&coords[t * 3 + 1]);
    i4 c = __builtin_nontemporal_load(&coords[t * 3 + 2]);
    uint32_t n0 = (uint32_t)(t * 4);
    uint32_t m0, m1, m2, m3;
    morton4(a, b, c, m0, m1, m2, m3);
    atomicMax(&tags[m0], n0 + 1u);
    atomicMax(&tags[m1], n0 + 2u);
    atomicMax(&tags[m2], n0 + 3u);
    atomicMax(&tags[m3], n0 + 4u);
}

__global__ void finalize(float* __restrict__ out, float* __restrict__ bf,
                         const float* __restrict__ density,
                         const float* __restrict__ sig) {
    int t = blockIdx.x * blockDim.x + threadIdx.x;
    const u4* tg4 = (const u4*)out;
    u4 tg0 = tg4[t * 2 + 0];
    u4 tg1 = tg4[t * 2 + 1];
    f4 d0 = __builtin_nontemporal_load(&((const f4*)density)[t * 2 + 0]);
    f4 d1 = __builtin_nontemporal_load(&((const f4*)density)[t * 2 + 1]);

    uint32_t tg[8] = {tg0.x, tg0.y, tg0.z, tg0.w, tg1.x, tg1.y, tg1.z, tg1.w};
    float    dd[8] = {d0.x, d0.y, d0.z, d0.w, d1.x, d1.y, d1.z, d1.w};
    float    nv[8];
    uint32_t byte = 0u;
#pragma unroll
    for (int i = 0; i < 8; ++i) {
        float d = dd[i];
        float v = d;
        uint32_t tag = tg[i];
        if (tag != 0u) {
            float s = sig[tag - 1u];
            if (d >= 0.0f && s >= 0.0f) v = fmaxf(d * 0.95f, s);
        }
        nv[i] = v;
        byte |= (v > 0.01f ? 1u : 0u) << i;
    }
    f4 o0 = {nv[0], nv[1], nv[2], nv[3]};
    f4 o1 = {nv[4], nv[5], nv[6], nv[7]};
    __builtin_nontemporal_store(o0, &((f4*)out)[t * 2 + 0]);
    __builtin_nontemporal_store(o1, &((f4*)out)[t * 2 + 1]);
    __builtin_nontemporal_store((float)byte, &bf[t]);
}

// ==================================================================================

extern "C" void kernel_launch(void* const* d_in, const int* in_sizes, int n_in,
                              void* d_out, int out_size, void* d_ws, size_t ws_size,
                              hipStream_t stream) {
    const float* density = (const float*)d_in[0];   // [3, 256^3] f32
    const float* sigmas  = (const float*)d_in[1];   // [3, 2^22]  f32
    const int*   coords  = (const int*)d_in[2];     // [3, 2^22, 3] i32
    float* out = (float*)d_out;

    // workspace: pair slabs 2048*2500*16 B = 81,920,000 | gcnt 3*2048*4 = 24,576
    const size_t OFF_CNT = (size_t)NBUK * CAP * 16ull;            // 81,920,000
    const size_t NEED    = OFF_CNT + (size_t)CASCADES * NBUK * 4ull;

    if (d_ws != nullptr && ws_size >= NEED) {
        char* w = (char*)d_ws;
        ull2*     pairs = (ull2*)w;
        uint32_t* gcnt  = (uint32_t*)(w + OFF_CNT);

        k_zero<<<(CASCADES * NBUK) / 512, 512, 0, stream>>>(gcnt);

        for (int c = 0; c < CASCADES; ++c) {
            const i4* cco = (const i4*)(coords + (size_t)c * NUM_COORDS * 3);
            const f4* sg4 = (const f4*)(sigmas + (size_t)c * NUM_COORDS);
            const f4* dg4 = (const f4*)(density + (size_t)c * G3);
            f4*       og4 = (f4*)(out + (size_t)c * G3);
            float*    ob  = out + GRID_ELEMS + (size_t)c * (G3 / 8);
            uint32_t* gc  = gcnt + (size_t)c * NBUK;

            k_scatter<<<NB,   KTHREADS, 0, stream>>>(cco, sg4, gc, pairs);
            k_final  <<<NBUK, KTHREADS, 0, stream>>>(pairs, gc, dg4, og4, ob);
        }
    } else {
        // fallback: round-1 verified cascade-chunked atomic path
        for (int c = 0; c < CASCADES; ++c) {
            uint32_t* tg   = (uint32_t*)d_out + (size_t)c * G3;
            const int* cco = coords + (size_t)c * NUM_COORDS * 3;
            float*     og  = out + (size_t)c * G3;
            float*     ob  = out + GRID_ELEMS + (size_t)c * (G3 / 8);
            const float* dg = density + (size_t)c * G3;
            const float* sg = sigmas  + (size_t)c * NUM_COORDS;

            clear_tags  <<<G3 / 4 / 256,         256, 0, stream>>>((u4*)tg);
            scatter_tags<<<NUM_COORDS / 4 / 256, 256, 0, stream>>>((const i4*)cco, tg);
            finalize    <<<G3 / 8 / 256,         256, 0, stream>>>(og, ob, dg, sg);
        }
    }
}